// Round 2
// baseline (123.916 us; speedup 1.0000x reference)
//
#include <hip/hip_runtime.h>

// DifferentiableFK: serial 63-body hinge chain, B=131072, fp32 in/out.
// R5 (42.5us): LDS output staging fixed write amplification (156->25MB).
// R6 (44.1us, NEUTRAL): tried to pin qpos row in regs with
// sched_barrier(0) -- FAILED, VGPR_Count stayed 68: sched_barrier only
// constrains within a scheduling region; MachineSink moved the 17 float4
// loads across basic blocks into the unrolled chain anyway. Kernel is
// latency-bound (VALUBusy 41%, HBM 12%, occupancy hard-capped at
// 2 waves/SIMD by grid size): ~17 exposed ~500-900cy VMEM latencies
// per thread inside the serial chain.
// R7:
//  (a) pin f[] residency with per-element asm volatile("" : "+v"(f[i]))
//      -- a load cannot sink past a USE of its result. One vmcnt drain
//      up front, then the 61-hinge chain is VMEM-free.
//      VERIFY: VGPR_Count must jump to >=110; if still 68 the pin failed.
//  (b) emit(): smask[bid] is wave-uniform but read via LDS->VGPR, making
//      the while-loop divergent and fragmenting scheduling regions.
//      readfirstlane -> SGPR -> scalar branches, bigger regions, better
//      cross-hinge pipelining of sincos / constant prefetch.

#define NBODY  63
#define NHINGE 61
#define NSITES 16
#define QDIM   68   // 7 + NHINGE
#define LSTRIDE 49  // 48 floats/thread + 1 pad: lane*49 mod 32 = lane*17 -> 2-way max (free)

__global__ __launch_bounds__(256, 2)
void fk_main(const float* __restrict__ qpos,
             const float* __restrict__ body_pos,
             const float* __restrict__ body_quat,
             const float* __restrict__ hinge_axis,
             const float* __restrict__ jnt_pos,
             const float* __restrict__ site_pos,
             const int* __restrict__ site_body,
             float* __restrict__ out, int nb)
{
    __shared__ float sbuf[256 * LSTRIDE];   // 50176 B output staging
    __shared__ float hc[NHINGE][16];        // 3904 B: u.wxyz, v.wxyz, (b+j).xyz_, j.xyz_
    __shared__ float spos[NSITES][4];       // 256 B
    __shared__ int   smask[NBODY];          // 252 B per-body site bitmask
    // total 54.6 KB/block -> 2 blocks/CU = 109 KB <= 160 KB

    const int tid = threadIdx.x;
    const int t = blockIdx.x * 256 + tid;
    float* my = sbuf + tid * LSTRIDE;

    // ---- 1. load the full qpos row (68 floats = 17 x float4) and PIN it ----
    float f[QDIM];
    if (t < nb) {
        const float4* q4 = reinterpret_cast<const float4*>(qpos) + (size_t)t * 17;
#pragma unroll
        for (int i = 0; i < 17; i++) {
            float4 v = q4[i];
            f[4*i+0] = v.x; f[4*i+1] = v.y; f[4*i+2] = v.z; f[4*i+3] = v.w;
        }
        // Residency pin: a use MachineSink cannot cross. Forces all 68
        // values into distinct VGPRs here; loads stay hoisted, one
        // vmcnt drain, chain below runs with zero VMEM stalls.
#pragma unroll
        for (int i = 0; i < QDIM; i++)
            asm volatile("" : "+v"(f[i]));
    }

    // ---- 2. per-block constant setup into LDS ----
    if (tid < NHINGE) {
        int h = tid, bid = h + 2;
        float uw = body_quat[bid*4+0], ux = body_quat[bid*4+1];
        float uy = body_quat[bid*4+2], uz = body_quat[bid*4+3];
        float ax = hinge_axis[h*3+0], ay = hinge_axis[h*3+1], az = hinge_axis[h*3+2];
        float jx = jnt_pos[h*3+0],   jy = jnt_pos[h*3+1],   jz = jnt_pos[h*3+2];
        float bx = body_pos[bid*3+0], by = body_pos[bid*3+1], bz = body_pos[bid*3+2];
        hc[h][0] = uw; hc[h][1] = ux; hc[h][2] = uy; hc[h][3] = uz;
        // v = body_quat (x) (0, axis)  -> local = cos*u + sin*v
        hc[h][4] = -(ux * ax + uy * ay + uz * az);
        hc[h][5] =  uw * ax + uy * az - uz * ay;
        hc[h][6] =  uw * ay - ux * az + uz * ax;
        hc[h][7] =  uw * az + ux * ay - uy * ax;
        hc[h][8] = bx + jx; hc[h][9] = by + jy; hc[h][10] = bz + jz; hc[h][11] = 0.f;
        hc[h][12] = jx; hc[h][13] = jy; hc[h][14] = jz; hc[h][15] = 0.f;
    }
    if (tid < NSITES) {
        spos[tid][0] = site_pos[tid*3+0];
        spos[tid][1] = site_pos[tid*3+1];
        spos[tid][2] = site_pos[tid*3+2];
        spos[tid][3] = 0.f;
    }
    if (tid < NBODY) {
        int m = 0;
#pragma unroll
        for (int s = 0; s < NSITES; s++)
            m |= (site_body[s] == tid) ? (1 << s) : 0;
        smask[tid] = m;
    }
    // which bodies own any site: uniform global loads -> SGPRs -> scalar branches
    unsigned long long bodymask = 0ull;
#pragma unroll
    for (int s = 0; s < NSITES; s++)
        bodymask |= 1ull << site_body[s];

    __syncthreads();   // LDS tables visible

    if (t < nb) {
        // ---- body 1: free joint ----
        float wpx = f[0], wpy = f[1], wpz = f[2];
        float qw = f[3], qx = f[4], qy = f[5], qz = f[6];
        float inv = rsqrtf(qw * qw + qx * qx + qy * qy + qz * qz);
        qw *= inv; qx *= inv; qy *= inv; qz *= inv;

        auto emit = [&](int bid) {
            // smask value is identical across the wave: lift to SGPR so the
            // site loop is scalar-branched (no exec-mask divergence, larger
            // scheduling regions across hinges).
            int m = __builtin_amdgcn_readfirstlane(smask[bid]);
            while (m) {
                int s = __ffs(m) - 1; m &= m - 1;
                float vx = spos[s][0], vy = spos[s][1], vz = spos[s][2];
                float tx = 2.f * (qy * vz - qz * vy);
                float ty = 2.f * (qz * vx - qx * vz);
                float tz = 2.f * (qx * vy - qy * vx);
                float* o = my + s * 3;    // LDS: 2-way bank alias max (free)
                o[0] = wpx + vx + qw * tx + (qy * tz - qz * ty);
                o[1] = wpy + vy + qw * ty + (qz * tx - qx * tz);
                o[2] = wpz + vz + qw * tz + (qx * ty - qy * tx);
            }
        };

        if (bodymask & 2ull) emit(1);

        // ---- serial hinge chain, fully unrolled, VMEM-free ----
#pragma unroll
        for (int h = 0; h < NHINGE; h++) {
            const int bid = h + 2;
            const float* c = hc[h];       // uniform LDS broadcasts, static offsets
            float ang = 0.5f * f[7 + h];
            float sn, cs;
            __sincosf(ang, &sn, &cs);
            // local = cs*u + sn*v
            float lw = cs * c[0] + sn * c[4];
            float lx = cs * c[1] + sn * c[5];
            float ly = cs * c[2] + sn * c[6];
            float lz = cs * c[3] + sn * c[7];
            // anchor = wp + qrot(wq, body_pos + jnt_pos)
            float ax = c[8], ay = c[9], az = c[10];
            float tx = 2.f * (qy * az - qz * ay);
            float ty = 2.f * (qz * ax - qx * az);
            float tz = 2.f * (qx * ay - qy * ax);
            float anx = wpx + ax + qw * tx + (qy * tz - qz * ty);
            float any_ = wpy + ay + qw * ty + (qz * tx - qx * tz);
            float anz = wpz + az + qw * tz + (qx * ty - qy * tx);
            // nq = qmul(wq, local)
            float nw = qw * lw - qx * lx - qy * ly - qz * lz;
            float nx = qw * lx + qx * lw + qy * lz - qz * ly;
            float ny = qw * ly - qx * lz + qy * lw + qz * lx;
            float nz = qw * lz + qx * ly - qy * lx + qz * lw;
            // wp = anchor - qrot(nq, jnt_pos)
            float jx = c[12], jy = c[13], jz = c[14];
            float t2x = 2.f * (ny * jz - nz * jy);
            float t2y = 2.f * (nz * jx - nx * jz);
            float t2z = 2.f * (nx * jy - ny * jx);
            wpx = anx - (jx + nw * t2x + (ny * t2z - nz * t2y));
            wpy = any_ - (jy + nw * t2y + (nz * t2x - nx * t2z));
            wpz = anz - (jz + nw * t2z + (nx * t2y - ny * t2x));
            qw = nw; qx = nx; qy = ny; qz = nz;

            if (bodymask & (1ull << bid)) emit(bid);
        }
    }

    __syncthreads();

    // ---- coalesced copy-out: block region = 256 threads * 48 floats = 48 KiB ----
    // float4 g (lane-consecutive): thread q = g/12, dword offs r = 4*(g%12);
    // each float4 stays inside one thread's 48-float region (48 % 4 == 0).
    {
        size_t blk_dw = (size_t)blockIdx.x * (256 * 48);
        if (blk_dw + 256 * 48 <= (size_t)nb * 48) {
            float4* out4 = reinterpret_cast<float4*>(out + blk_dw);
#pragma unroll
            for (int k = 0; k < 12; k++) {
                int g = k * 256 + tid;
                int q = g / 12;
                int r = (g - q * 12) * 4;
                const float* p = sbuf + q * LSTRIDE + r;
                float4 v = { p[0], p[1], p[2], p[3] };
                out4[g] = v;   // 64 lanes x 16B contiguous = 1 KiB/instr
            }
        } else if (t < nb) {
            // tail fallback (not taken at nb=131072): scalar copy
            for (int k = 0; k < 48; k++) out[(size_t)t * 48 + k] = my[k];
        }
    }
}

extern "C" void kernel_launch(void* const* d_in, const int* in_sizes, int n_in,
                              void* d_out, int out_size, void* d_ws, size_t ws_size,
                              hipStream_t stream)
{
    const float* qpos       = (const float*)d_in[0];
    const float* body_pos   = (const float*)d_in[1];
    const float* body_quat  = (const float*)d_in[2];
    const float* hinge_axis = (const float*)d_in[3];
    const float* jnt_pos    = (const float*)d_in[4];
    const float* site_pos   = (const float*)d_in[5];
    // d_in[6] = body_parent: max(arange-1,0) by construction -> serial chain, unused
    const int* site_body    = (const int*)d_in[7];

    int nb = in_sizes[0] / QDIM;   // 131072

    fk_main<<<(nb + 255) / 256, 256, 0, stream>>>(qpos, body_pos, body_quat,
                                                  hinge_axis, jnt_pos, site_pos,
                                                  site_body, (float*)d_out, nb);
}

// Round 3
// 117.926 us; speedup vs baseline: 1.0508x; 1.0508x over previous
//
#include <hip/hip_runtime.h>

// DifferentiableFK: serial 63-body hinge chain, B=131072, fp32 in/out.
// R5 (42.5us): LDS output staging fixed write amplification (156->25MB).
// R6 (44.1us, NEUTRAL): sched_barrier(0) pin failed (MachineSink crosses BBs).
// R7 (122us, REGRESSED): asm volatile "+v" pins on f[68] -> allocator kept
//   VGPR=68 and spilled f[] to SCRATCH (L2-resident: no HBM delta, 3x time,
//   VALUBusy 15%). Lesson: cannot force 68-float residency across a 4000-inst
//   body; the allocator wins.
// R8 theory: the 44us plateau is INSTRUCTION-FETCH bound. Fully-unrolled
//   chain + 12 inlined emits ~= 35-40KB straight-line code > 32KB I$;
//   every wave streams it once from L2 (~200cy/line) ~= 100K cy ~= 42us --
//   matches measurement, explains R5==R6 and VALUBusy ~40% with no VMEM
//   pressure. Fix: ROLL the chain into a loop (5 iters x 12 hinges,
//   ~12KB body, I$-resident, 5x reuse). The compile-time-index blocker on
//   f[7+h] is solved by a software-pipelined rolling window of 3 float4
//   chunks in named registers: loads for iter j+1 issued at top of iter j
//   (~500cy in-flight over 12 hinges; 2 waves/SIMD cover the rest).
//   Loads cannot sink past the loop-carried consume -> pipeline survives.
// VERIFY: VGPR_Count ~90-110, VALUBusy 60%+, fk_main 14-22us.

#define NBODY  63
#define NHINGE 61
#define NSITES 16
#define QDIM   68   // 7 + NHINGE
#define LSTRIDE 49  // 48 floats/thread + 1 pad: lane*49 mod 32 -> 2-way max (free)

typedef unsigned long long u64;

__global__ __launch_bounds__(256, 2)
void fk_main(const float* __restrict__ qpos,
             const float* __restrict__ body_pos,
             const float* __restrict__ body_quat,
             const float* __restrict__ hinge_axis,
             const float* __restrict__ jnt_pos,
             const float* __restrict__ site_pos,
             const int* __restrict__ site_body,
             float* __restrict__ out, int nb)
{
    __shared__ float sbuf[256 * LSTRIDE];   // 50176 B output staging
    __shared__ float hc[NHINGE][16];        // u.wxyz, v.wxyz, (b+j).xyz_, j.xyz_
    __shared__ float spos[NSITES][4];
    __shared__ int   smask[NBODY];
    // total 54.6 KB/block -> 2 blocks/CU

    const int tid = threadIdx.x;
    const int t = blockIdx.x * 256 + tid;
    float* my = sbuf + tid * LSTRIDE;

    // ---- per-block constant setup into LDS ----
    if (tid < NHINGE) {
        int h = tid, bid = h + 2;
        float uw = body_quat[bid*4+0], ux = body_quat[bid*4+1];
        float uy = body_quat[bid*4+2], uz = body_quat[bid*4+3];
        float ax = hinge_axis[h*3+0], ay = hinge_axis[h*3+1], az = hinge_axis[h*3+2];
        float jx = jnt_pos[h*3+0],   jy = jnt_pos[h*3+1],   jz = jnt_pos[h*3+2];
        float bx = body_pos[bid*3+0], by = body_pos[bid*3+1], bz = body_pos[bid*3+2];
        hc[h][0] = uw; hc[h][1] = ux; hc[h][2] = uy; hc[h][3] = uz;
        // v = body_quat (x) (0, axis) -> local = cos*u + sin*v
        hc[h][4] = -(ux * ax + uy * ay + uz * az);
        hc[h][5] =  uw * ax + uy * az - uz * ay;
        hc[h][6] =  uw * ay - ux * az + uz * ax;
        hc[h][7] =  uw * az + ux * ay - uy * ax;
        hc[h][8] = bx + jx; hc[h][9] = by + jy; hc[h][10] = bz + jz; hc[h][11] = 0.f;
        hc[h][12] = jx; hc[h][13] = jy; hc[h][14] = jz; hc[h][15] = 0.f;
    }
    if (tid < NSITES) {
        spos[tid][0] = site_pos[tid*3+0];
        spos[tid][1] = site_pos[tid*3+1];
        spos[tid][2] = site_pos[tid*3+2];
        spos[tid][3] = 0.f;
    }
    if (tid < NBODY) {
        int m = 0;
#pragma unroll
        for (int s = 0; s < NSITES; s++)
            m |= (site_body[s] == tid) ? (1 << s) : 0;
        smask[tid] = m;
    }
    // uniform global loads -> SGPRs -> scalar branches
    u64 bodymask = 0ull;
#pragma unroll
    for (int s = 0; s < NSITES; s++)
        bodymask |= 1ull << site_body[s];

    __syncthreads();

    if (t < nb) {
        const float4* q4 = reinterpret_cast<const float4*>(qpos) + (size_t)t * 17;
        // chunk0 = (px,py,pz,qw); chunk1 = (qx,qy,qz,a0); chunk k>=2 = a[4k-7..4k-4]
        float4 c0 = q4[0];
        float4 c1 = q4[1];
        float4 w0 = q4[2], w1 = q4[3], w2 = q4[4];   // rolling window prefill

        // ---- body 1: free joint ----
        float wpx = c0.x, wpy = c0.y, wpz = c0.z;
        float qw = c0.w, qx = c1.x, qy = c1.y, qz = c1.z;
        float inv = rsqrtf(qw * qw + qx * qx + qy * qy + qz * qz);
        qw *= inv; qx *= inv; qy *= inv; qz *= inv;

        auto emit = [&](int bid) {
            int m = __builtin_amdgcn_readfirstlane(smask[bid]);  // wave-uniform
            while (m) {
                int s = __ffs(m) - 1; m &= m - 1;
                float vx = spos[s][0], vy = spos[s][1], vz = spos[s][2];
                float tx = 2.f * (qy * vz - qz * vy);
                float ty = 2.f * (qz * vx - qx * vz);
                float tz = 2.f * (qx * vy - qy * vx);
                float* o = my + s * 3;    // LDS: 2-way bank alias max (free)
                o[0] = wpx + vx + qw * tx + (qy * tz - qz * ty);
                o[1] = wpy + vy + qw * ty + (qz * tx - qx * tz);
                o[2] = wpz + vz + qw * tz + (qx * ty - qy * tx);
            }
        };

        auto hinge = [&](int h, float angle) {
            const float* c = hc[h];       // uniform LDS broadcast (runtime h ok)
            float sn, cs;
            __sincosf(0.5f * angle, &sn, &cs);
            float lw = cs * c[0] + sn * c[4];
            float lx = cs * c[1] + sn * c[5];
            float ly = cs * c[2] + sn * c[6];
            float lz = cs * c[3] + sn * c[7];
            float ax = c[8], ay = c[9], az = c[10];
            float tx = 2.f * (qy * az - qz * ay);
            float ty = 2.f * (qz * ax - qx * az);
            float tz = 2.f * (qx * ay - qy * ax);
            float anx = wpx + ax + qw * tx + (qy * tz - qz * ty);
            float any_ = wpy + ay + qw * ty + (qz * tx - qx * tz);
            float anz = wpz + az + qw * tz + (qx * ty - qy * tx);
            float nw = qw * lw - qx * lx - qy * ly - qz * lz;
            float nx = qw * lx + qx * lw + qy * lz - qz * ly;
            float ny = qw * ly - qx * lz + qy * lw + qz * lx;
            float nz = qw * lz + qx * ly - qy * lx + qz * lw;
            float jx = c[12], jy = c[13], jz = c[14];
            float t2x = 2.f * (ny * jz - nz * jy);
            float t2y = 2.f * (nz * jx - nx * jz);
            float t2z = 2.f * (nx * jy - ny * jx);
            wpx = anx - (jx + nw * t2x + (ny * t2z - nz * t2y));
            wpy = any_ - (jy + nw * t2y + (nz * t2x - nx * t2z));
            wpz = anz - (jz + nw * t2z + (nx * t2y - ny * t2x));
            qw = nw; qx = nx; qy = ny; qz = nz;
        };

        if (bodymask & 2ull) emit(1);
        hinge(0, c1.w);                       // hinge 0 angle rides in chunk1.w
        if (bodymask & 4ull) emit(2);

        // ---- rolled chain: 5 iters x 12 hinges, software-pipelined loads ----
#pragma clang loop unroll(disable)
        for (int j = 0; j < 5; ++j) {
            // issue next 3 chunks NOW; consumed after the 12 hinges below.
            int kb = 5 + 3 * j;
            float4 n0 = q4[kb     > 16 ? 16 : kb    ];   // clamped tail dup-loads,
            float4 n1 = q4[kb + 1 > 16 ? 16 : kb + 1];   // values unused past a60
            float4 n2 = q4[kb + 2 > 16 ? 16 : kb + 2];

            float ang[12] = { w0.x, w0.y, w0.z, w0.w,
                              w1.x, w1.y, w1.z, w1.w,
                              w2.x, w2.y, w2.z, w2.w };
            int h0 = 1 + 12 * j;
#pragma unroll
            for (int m = 0; m < 12; ++m) {
                int h = h0 + m;               // uniform (scalar) index
                hinge(h, ang[m]);
                int bid = h + 2;
                if ((bodymask >> bid) & 1ull) emit(bid);   // scalar branch
            }
            w0 = n0; w1 = n1; w2 = n2;        // rotate window (vmcnt waits here)
        }
    }

    __syncthreads();

    // ---- coalesced copy-out: block region = 256 threads * 48 floats = 48 KiB ----
    {
        size_t blk_dw = (size_t)blockIdx.x * (256 * 48);
        if (blk_dw + 256 * 48 <= (size_t)nb * 48) {
            float4* out4 = reinterpret_cast<float4*>(out + blk_dw);
#pragma unroll
            for (int k = 0; k < 12; k++) {
                int g = k * 256 + tid;
                int q = g / 12;
                int r = (g - q * 12) * 4;
                const float* p = sbuf + q * LSTRIDE + r;
                float4 v = { p[0], p[1], p[2], p[3] };
                out4[g] = v;   // 64 lanes x 16B contiguous = 1 KiB/instr
            }
        } else if (t < nb) {
            // tail fallback (not taken at nb=131072)
            for (int k = 0; k < 48; k++) out[(size_t)t * 48 + k] = my[k];
        }
    }
}

extern "C" void kernel_launch(void* const* d_in, const int* in_sizes, int n_in,
                              void* d_out, int out_size, void* d_ws, size_t ws_size,
                              hipStream_t stream)
{
    const float* qpos       = (const float*)d_in[0];
    const float* body_pos   = (const float*)d_in[1];
    const float* body_quat  = (const float*)d_in[2];
    const float* hinge_axis = (const float*)d_in[3];
    const float* jnt_pos    = (const float*)d_in[4];
    const float* site_pos   = (const float*)d_in[5];
    // d_in[6] = body_parent: max(arange-1,0) by construction -> serial chain, unused
    const int* site_body    = (const int*)d_in[7];

    int nb = in_sizes[0] / QDIM;   // 131072

    fk_main<<<(nb + 255) / 256, 256, 0, stream>>>(qpos, body_pos, body_quat,
                                                  hinge_axis, jnt_pos, site_pos,
                                                  site_body, (float*)d_out, nb);
}